// Round 4
// baseline (167.311 us; speedup 1.0000x reference)
//
#include <hip/hip_runtime.h>
#include <stdint.h>

#define B_    16
#define CIN_  128
#define COUT_ 128
#define H_    64
#define W_    64
#define L_    4096
#define KK_   1152
#define PW_   66                 // padded image dim (halo 1 each side)
#define PPIX_ (PW_ * PW_)        // 4356

typedef unsigned short u16;
typedef __bf16 bf16x8 __attribute__((ext_vector_type(8)));
typedef float  floatx4 __attribute__((ext_vector_type(4)));
typedef uint32_t u32x4 __attribute__((ext_vector_type(4)));

typedef const __attribute__((address_space(1))) uint32_t* gptr_t;
typedef __attribute__((address_space(3))) uint32_t*       lptr_t;

__device__ __forceinline__ void async_copy16(const void* g, void* l) {
    // stages 64 lanes x 16 B = 1024 B; LDS dest = wave-uniform base + lane*16
    __builtin_amdgcn_global_load_lds((gptr_t)g, (lptr_t)l, 16, 0, 0);
}

__device__ __forceinline__ u16 f2bf(float f) {
    uint32_t u = __builtin_bit_cast(uint32_t, f);
    uint32_t r = u + 0x7FFFu + ((u >> 16) & 1u);   // round-to-nearest-even
    return (u16)(r >> 16);
}

// ---------------------------------------------------------------------------
// Fused prep: blocks 0..1023   -> transpose x -> xTp [B][66][66][CIN] bf16
//             blocks 1024..1151 -> mb[o][l] = bias[o] + sum_k mw[o][k]*mask[k][l]
//             blocks 1152..1215 -> wb2[k][o][c] = bf16(weight[o][c][k])
// ---------------------------------------------------------------------------
__global__ void lmc_prep_kernel(const float* __restrict__ x,
                                const float* __restrict__ mask, const float* __restrict__ mw,
                                const float* __restrict__ bias, const float* __restrict__ w,
                                u16* __restrict__ xTp, float* __restrict__ mb,
                                u16* __restrict__ wb2) {
    const int bid = blockIdx.x, tid = threadIdx.x;
    if (bid < 1024) {
        // ---- transpose: x [B][CIN][64][64] f32 -> xTp bf16, halo zeroed ----
        __shared__ u16 tile[64][CIN_ + 8];
        const int b = bid >> 6;
        const int y = bid & 63;

        {
            const int c  = tid >> 1;
            const int x0 = (tid & 1) * 32;
            const float* src = x + ((size_t)b * CIN_ + c) * L_ + y * 64 + x0;
            #pragma unroll
            for (int j = 0; j < 32; j += 4) {
                float4 v = *reinterpret_cast<const float4*>(src + j);
                tile[x0 + j + 0][c] = f2bf(v.x);
                tile[x0 + j + 1][c] = f2bf(v.y);
                tile[x0 + j + 2][c] = f2bf(v.z);
                tile[x0 + j + 3][c] = f2bf(v.w);
            }
        }
        __syncthreads();

        u16* dstrow = xTp + ((size_t)(b * PW_ + (y + 1)) * PW_) * CIN_;  // pixel (y+1, 0)
        {
            const int xx   = tid >> 2;
            const int cseg = (tid & 3) * 32;
            u16* dst = dstrow + (size_t)(xx + 1) * CIN_ + cseg;
            #pragma unroll
            for (int i = 0; i < 32; i += 8) {
                *reinterpret_cast<uint4*>(dst + i) =
                    *reinterpret_cast<const uint4*>(&tile[xx][cseg + i]);
            }
        }
        const uint4 z = {0u, 0u, 0u, 0u};
        if (tid < 32) {
            const int pix = (tid >> 4) ? 65 : 0;
            *reinterpret_cast<uint4*>(dstrow + (size_t)pix * CIN_ + (tid & 15) * 8) = z;
        }
        if (y == 0 || y == 63) {
            u16* brow = xTp + ((size_t)(b * PW_ + (y == 0 ? 0 : 65)) * PW_) * CIN_;
            for (int i = tid; i < (PW_ * CIN_) / 8; i += 256)   // 1056 uint4
                reinterpret_cast<uint4*>(brow)[i] = z;
        }
    } else if (bid < 1152) {
        // ---- mb ----
        const int o = bid - 1024;
        float m[9];
        #pragma unroll
        for (int k = 0; k < 9; ++k) m[k] = mw[o * 9 + k];
        const float bs = bias[o];
        for (int l = tid; l < L_; l += 256) {
            float s = bs;
            #pragma unroll
            for (int k = 0; k < 9; ++k) s += m[k] * mask[k * L_ + l];
            mb[o * L_ + l] = s;
        }
    } else {
        // ---- wb2 repack ----
        const int base = (bid - 1152) * 2304;
        #pragma unroll
        for (int i = 0; i < 9; ++i) {
            const int e = base + i * 256 + tid;        // 0..147455 exact
            const int k = e >> 14;                     // /16384
            const int rem = e & 16383;
            const int o = rem >> 7, c = rem & 127;
            wb2[e] = f2bf(w[(size_t)o * KK_ + c * 9 + k]);
        }
    }
}

// ---------------------------------------------------------------------------
// Main GEMM, window-resident, 8 waves, 4 waves/SIMD.
// Block = 128(o) x 128(l) = 2 image rows; window 4x66 = 264 px = 67.6 KB LDS.
// 512 blocks -> exactly 2 blocks/CU (one balanced generation), 16 waves/CU.
// 8 waves of 64(o) x 32(l): i-extent stays 4 => total ds_read count unchanged
// vs the 4-wave version, but per-wave register state fits 128 VGPR:
//   acc 4x2 (32) + A 2-slice roll af2[4][2] (32) + B 1-step prefetch (16).
// A slice for global step g is loaded at step g-2 (~16 MFMAs ahead: covers L2
// latency). B frag for step g loaded at g-1 (~8 MFMAs ahead: covers LDS).
// All register-array indices are literal after unroll (rule #20).
// Mask applied as bitwise AND on B-fragments (mask is binary -> exact).
// ---------------------------------------------------------------------------
#define SH_(k) (((k) / 3 - 1) * 66 + ((k) % 3 - 1))

// one pipeline step, global step g = k*4+ks (ks is a literal 0..3).
//  - prefetch B frag for step g+1 into nxt (2 ds_read_b128)
//  - mask-AND cur, 8 MFMAs with A parity slot (ks&1)
//  - roll A parity slot to slice g+2 (4 x 16B global loads, wb2 L1/L2-hot)
#define GSTEP(k, ks, cur, nxt)                                                \
    do {                                                                      \
        const int g_ = (k) * 4 + (ks);                                        \
        if (g_ < 35) {                                                        \
            const int gn_  = g_ + 1;                                          \
            const int shn_ = SH_(gn_ >> 2);                                   \
            _Pragma("unroll")                                                 \
            for (int j = 0; j < 2; ++j) {                                     \
                const int pixn  = pix0[j] + shn_;                             \
                const int slotn = ((gn_ & 3) * 4 + quad) ^ (pixn & 7);        \
                nxt[j] = *reinterpret_cast<const bf16x8*>(                    \
                            &W_lds[pixn * 128 + slotn * 8]);                  \
            }                                                                 \
        }                                                                     \
        bf16x8 bm[2];                                                         \
        _Pragma("unroll")                                                     \
        for (int j = 0; j < 2; ++j) {                                         \
            u32x4 t = __builtin_bit_cast(u32x4, cur[j]);                      \
            t &= (0u - (uint32_t)((bits >> ((k) * 2 + j)) & 1u));             \
            bm[j] = __builtin_bit_cast(bf16x8, t);                            \
        }                                                                     \
        _Pragma("unroll")                                                     \
        for (int i = 0; i < 4; ++i)                                           \
            _Pragma("unroll")                                                 \
            for (int j = 0; j < 2; ++j)                                       \
                acc[i][j] = __builtin_amdgcn_mfma_f32_16x16x32_bf16(          \
                    af2[i][(ks) & 1], bm[j], acc[i][j], 0, 0, 0);             \
        {                                                                     \
            const int gr_ = (g_ + 2 > 35) ? 35 : g_ + 2;                      \
            const int ro_ = (gr_ >> 2) * 16384 + (gr_ & 3) * 32;              \
            _Pragma("unroll")                                                 \
            for (int i = 0; i < 4; ++i)                                       \
                af2[i][(ks) & 1] = *reinterpret_cast<const bf16x8*>(          \
                    wb2 + ro_ + arow[i]);                                     \
        }                                                                     \
    } while (0)

__global__ __launch_bounds__(512, 4)
void lmc_gemm_kernel(const u16* __restrict__ xTp, const u16* __restrict__ wb2,
                     const float* __restrict__ mask, const float* __restrict__ mb,
                     float* __restrict__ out) {
    __shared__ u16 W_lds[264 * 128];   // 67,584 B -> 2 blocks/CU

    // XCD-chunked bijective swizzle (512 blocks, 8 XCDs): XCD X gets logical
    // [64X, 64X+64) = 2 whole batches -> per-XCD xTp working set ~2.2 MB.
    const int flat    = blockIdx.x;                  // 0..511
    const int logical = (flat & 7) * 64 + (flat >> 3);
    const int b       = logical >> 5;
    const int lt      = logical & 31;                // 0..31
    const int Y       = lt * 2;                      // first image row of tile
    const int l0      = lt * 128;

    const int tid  = threadIdx.x;
    const int lane = tid & 63;
    const int wv   = tid >> 6;                       // 0..7
    const int wm   = (wv >> 2) * 64;                 // o offset  {0,64}
    const int wn   = (wv & 3) * 32;                  // l offset  {0,32,64,96}
    const int lrow = lane & 15;
    const int quad = lane >> 4;

    // ---- prologue: stage 4x66 pixel window (padded rows Y..Y+3) ----
    // window pixel p: LDS slot s holds data chunk s^(p&7); linear LDS dest,
    // swizzle applied on the global source chunk.
    {
        const char* xw = (const char*)xTp + ((size_t)(b * PW_ + Y) * PW_) * 256;
        for (int t = wv; t < 66; t += 8) {           // 66 instrs, 4 px each
            const int p    = t * 4 + quad;
            const int srcc = lrow ^ (p & 7);
            async_copy16(xw + (size_t)p * 256 + srcc * 16,
                         (char*)W_lds + t * 1024);
        }
    }

    // ---- A: 2-slice rolling register buffer (slices g=0 and g=1) ----
    int arow[4];
    #pragma unroll
    for (int i = 0; i < 4; ++i)
        arow[i] = (wm + i * 16 + lrow) * 128 + quad * 8;

    bf16x8 af2[4][2];
    #pragma unroll
    for (int i = 0; i < 4; ++i) {
        af2[i][0] = *reinterpret_cast<const bf16x8*>(wb2 + arow[i]);        // g=0: tap0 ks0
        af2[i][1] = *reinterpret_cast<const bf16x8*>(wb2 + arow[i] + 32);   // g=1: tap0 ks1
    }

    // ---- per-lane window pixel bases + mask bit-pack (18 bits) ----
    int pix0[2];
    uint32_t bits = 0;
    #pragma unroll
    for (int j = 0; j < 2; ++j) {
        const int ll = wn + j * 16 + lrow;           // block-local l 0..127
        pix0[j] = ((ll >> 6) + 1) * 66 + (ll & 63) + 1;
        const int lg = l0 + ll;
        #pragma unroll
        for (int k = 0; k < 9; ++k)
            if (mask[k * L_ + lg] != 0.0f) bits |= (1u << (k * 2 + j));
    }

    floatx4 acc[4][2];
    #pragma unroll
    for (int i = 0; i < 4; ++i)
        #pragma unroll
        for (int j = 0; j < 2; ++j)
            acc[i][j] = (floatx4){0.f, 0.f, 0.f, 0.f};

    __syncthreads();   // drains window staging; the ONLY barrier

    // ---- preload B frag for step g=0 ----
    bf16x8 bA[2], bB[2];
    {
        const int sh0 = SH_(0);
        #pragma unroll
        for (int j = 0; j < 2; ++j) {
            const int pix  = pix0[j] + sh0;
            const int slot = quad ^ (pix & 7);
            bA[j] = *reinterpret_cast<const bf16x8*>(&W_lds[pix * 128 + slot * 8]);
        }
    }

    // ---- main loop: 36 software-pipelined steps, no barriers ----
    #pragma unroll
    for (int k = 0; k < 9; ++k) {
        GSTEP(k, 0, bA, bB);
        GSTEP(k, 1, bB, bA);
        GSTEP(k, 2, bA, bB);
        GSTEP(k, 3, bB, bA);
    }

    // ---- epilogue: C/D layout col = lane&15 (l), row = quad*4 + r (o) ----
    #pragma unroll
    for (int i = 0; i < 4; ++i) {
        #pragma unroll
        for (int j = 0; j < 2; ++j) {
            const int l = l0 + wn + j * 16 + lrow;
            #pragma unroll
            for (int r = 0; r < 4; ++r) {
                const int o = wm + i * 16 + quad * 4 + r;
                out[((size_t)b * COUT_ + o) * L_ + l] = acc[i][j][r] + mb[o * L_ + l];
            }
        }
    }
}

// ---------------------------------------------------------------------------
extern "C" void kernel_launch(void* const* d_in, const int* in_sizes, int n_in,
                              void* d_out, int out_size, void* d_ws, size_t ws_size,
                              hipStream_t stream) {
    const float* x      = (const float*)d_in[0];
    const float* mask   = (const float*)d_in[1];
    const float* weight = (const float*)d_in[2];
    const float* mw     = (const float*)d_in[3];
    const float* bias   = (const float*)d_in[4];
    float* out = (float*)d_out;

    char* ws = (char*)d_ws;
    u16*   xTp = (u16*)ws;                                  // 16*4356*128*2 = 17,842,176 B
    u16*   wb2 = (u16*)(ws + 17842176);                     // 294,912 B  [9][128][128] bf16
    float* mb  = (float*)(ws + 17842176 + 294912);          // 2,097,152 B [128][4096] f32

    lmc_prep_kernel<<<1216, 256, 0, stream>>>(x, mask, mw, bias, weight, xTp, mb, wb2);
    lmc_gemm_kernel<<<512, 512, 0, stream>>>(xTp, wb2, mask, mb, out);
}

// Round 5
// 123.468 us; speedup vs baseline: 1.3551x; 1.3551x over previous
//
#include <hip/hip_runtime.h>
#include <stdint.h>

#define B_    16
#define CIN_  128
#define COUT_ 128
#define H_    64
#define W_    64
#define L_    4096
#define KK_   1152
#define PW_   66                 // padded image dim (halo 1 each side)
#define PPIX_ (PW_ * PW_)        // 4356

typedef unsigned short u16;
typedef __bf16 bf16x8 __attribute__((ext_vector_type(8)));
typedef float  floatx4 __attribute__((ext_vector_type(4)));
typedef uint32_t u32x4 __attribute__((ext_vector_type(4)));

typedef const __attribute__((address_space(1))) uint32_t* gptr_t;
typedef __attribute__((address_space(3))) uint32_t*       lptr_t;

__device__ __forceinline__ void async_copy16(const void* g, void* l) {
    // stages 64 lanes x 16 B = 1024 B; LDS dest = wave-uniform base + lane*16
    __builtin_amdgcn_global_load_lds((gptr_t)g, (lptr_t)l, 16, 0, 0);
}

__device__ __forceinline__ u16 f2bf(float f) {
    uint32_t u = __builtin_bit_cast(uint32_t, f);
    uint32_t r = u + 0x7FFFu + ((u >> 16) & 1u);   // round-to-nearest-even
    return (u16)(r >> 16);
}

// ---------------------------------------------------------------------------
// Fused prep: blocks 0..1023   -> transpose x -> xTp [B][66][66][CIN] bf16
//             blocks 1024..1151 -> mb[o][l] = bias[o] + sum_k mw[o][k]*mask[k][l]
//             blocks 1152..1215 -> wb2[k][o][c] = bf16(weight[o][c][k])
// ---------------------------------------------------------------------------
__global__ void lmc_prep_kernel(const float* __restrict__ x,
                                const float* __restrict__ mask, const float* __restrict__ mw,
                                const float* __restrict__ bias, const float* __restrict__ w,
                                u16* __restrict__ xTp, float* __restrict__ mb,
                                u16* __restrict__ wb2) {
    const int bid = blockIdx.x, tid = threadIdx.x;
    if (bid < 1024) {
        // ---- transpose: x [B][CIN][64][64] f32 -> xTp bf16, halo zeroed ----
        __shared__ u16 tile[64][CIN_ + 8];
        const int b = bid >> 6;
        const int y = bid & 63;

        {
            const int c  = tid >> 1;
            const int x0 = (tid & 1) * 32;
            const float* src = x + ((size_t)b * CIN_ + c) * L_ + y * 64 + x0;
            #pragma unroll
            for (int j = 0; j < 32; j += 4) {
                float4 v = *reinterpret_cast<const float4*>(src + j);
                tile[x0 + j + 0][c] = f2bf(v.x);
                tile[x0 + j + 1][c] = f2bf(v.y);
                tile[x0 + j + 2][c] = f2bf(v.z);
                tile[x0 + j + 3][c] = f2bf(v.w);
            }
        }
        __syncthreads();

        u16* dstrow = xTp + ((size_t)(b * PW_ + (y + 1)) * PW_) * CIN_;  // pixel (y+1, 0)
        {
            const int xx   = tid >> 2;
            const int cseg = (tid & 3) * 32;
            u16* dst = dstrow + (size_t)(xx + 1) * CIN_ + cseg;
            #pragma unroll
            for (int i = 0; i < 32; i += 8) {
                *reinterpret_cast<uint4*>(dst + i) =
                    *reinterpret_cast<const uint4*>(&tile[xx][cseg + i]);
            }
        }
        const uint4 z = {0u, 0u, 0u, 0u};
        if (tid < 32) {
            const int pix = (tid >> 4) ? 65 : 0;
            *reinterpret_cast<uint4*>(dstrow + (size_t)pix * CIN_ + (tid & 15) * 8) = z;
        }
        if (y == 0 || y == 63) {
            u16* brow = xTp + ((size_t)(b * PW_ + (y == 0 ? 0 : 65)) * PW_) * CIN_;
            for (int i = tid; i < (PW_ * CIN_) / 8; i += 256)   // 1056 uint4
                reinterpret_cast<uint4*>(brow)[i] = z;
        }
    } else if (bid < 1152) {
        // ---- mb ----
        const int o = bid - 1024;
        float m[9];
        #pragma unroll
        for (int k = 0; k < 9; ++k) m[k] = mw[o * 9 + k];
        const float bs = bias[o];
        for (int l = tid; l < L_; l += 256) {
            float s = bs;
            #pragma unroll
            for (int k = 0; k < 9; ++k) s += m[k] * mask[k * L_ + l];
            mb[o * L_ + l] = s;
        }
    } else {
        // ---- wb2 repack ----
        const int base = (bid - 1152) * 2304;
        #pragma unroll
        for (int i = 0; i < 9; ++i) {
            const int e = base + i * 256 + tid;        // 0..147455 exact
            const int k = e >> 14;                     // /16384
            const int rem = e & 16383;
            const int o = rem >> 7, c = rem & 127;
            wb2[e] = f2bf(w[(size_t)o * KK_ + c * 9 + k]);
        }
    }
}

// ---------------------------------------------------------------------------
// Main GEMM: ALL-LDS inner loop (no global loads in the loop at all).
// Block = 128(o) x 256(l) = 4 image rows; window 6x66 = 396 px = 101,376 B,
// staged ONCE. A (wb2) staged into a 2 x 16 KB LDS double-buffer at half-tap
// (64-c) granularity via global_load_lds from L2-hot wb2.
// 18 half-steps; each: issue 2 async copies for half-step g+1, then pure
// ds_read (8 A + 8 B) + 32 MFMA, then __syncthreads. The barrier's vmcnt(0)
// drain lands ~1300 cy after issue -> L2 latency fully covered. The compiler's
// fine-grained lgkmcnt handles ds_read->MFMA (the one schedule it does well);
// no register pipelining across steps (R2/R3/R4 showed hipcc collapses it).
// 256 blocks (16b x 16lt) x 512 thr (8 waves of 64x64) -> exactly 1 block/CU.
// Mask applied as bitwise AND on B-fragments (mask is binary -> exact).
// ---------------------------------------------------------------------------
__global__ __launch_bounds__(512, 2)
void lmc_gemm_kernel(const u16* __restrict__ xTp, const u16* __restrict__ wb2,
                     const float* __restrict__ mask, const float* __restrict__ mb,
                     float* __restrict__ out) {
    __shared__ u16 W_lds[396 * 128];      // 101,376 B window  [pix][c], XOR-8 chunk swizzle
    __shared__ u16 A_lds[2][128 * 64];    // 2 x 16,384 B half-tap A  [o][c-half], XOR-8

    // XCD-chunked bijective swizzle (256 blocks, 8 XCDs): XCD X gets logical
    // [32X, 32X+32) = 2 whole batches -> per-XCD xTp working set ~2.2 MB.
    const int flat    = blockIdx.x;                  // 0..255
    const int logical = (flat & 7) * 32 + (flat >> 3);
    const int b       = logical >> 4;
    const int lt      = logical & 15;
    const int Y       = lt * 4;                      // first image row of tile
    const int l0      = lt * 256;

    const int tid  = threadIdx.x;
    const int lane = tid & 63;
    const int wv   = tid >> 6;                       // 0..7
    const int wm   = (wv >> 2) * 64;                 // o offset  {0,64}
    const int wn   = (wv & 3) * 64;                  // l offset  {0,64,128,192}
    const int lrow = lane & 15;
    const int quad = lane >> 4;

    const char* wb2_c = (const char*)wb2;
    char* A_c = (char*)A_lds;

    // ---- stage 6x66 pixel window (rows Y..Y+5): 99 x 1 KB instrs ----
    // window pixel p: LDS slot s (16B chunks) holds data chunk s^(p&7);
    // linear LDS dest, swizzle applied on the global source chunk.
    {
        const char* xw = (const char*)xTp + ((size_t)(b * PW_ + Y) * PW_) * 256;
        for (int t = wv; t < 99; t += 8) {
            const int p    = t * 4 + quad;
            const int srcc = lrow ^ (p & 7);
            async_copy16(xw + (size_t)p * 256 + srcc * 16,
                         (char*)W_lds + t * 1024);
        }
    }

    // ---- A staging geometry (g-invariant per-lane source offsets) ----
    // LDS A row o (128 B = 8 chunks): slot s holds source chunk s^(o&7).
    // instr t covers rows 8t..8t+7; lane l -> row 8t+(l>>3), slot l&7.
    const int ao  = (lane >> 3);                          // row-in-8 group
    const int ach = (lane & 7) ^ (ao & 7);                // source chunk
    const int aoff0 = (8 * wv + ao) * 256 + ach * 16;     // t = wv
    // t = wv+8 source offset = aoff0 + 64*256 (64 rows later)
    // ---- stage A half-step 0 (tap 0, c[0:64)) into buffer 0 ----
    async_copy16(wb2_c + aoff0,         A_c + wv * 1024);
    async_copy16(wb2_c + aoff0 + 16384, A_c + wv * 1024 + 8192);

    // ---- per-lane window pixel bases + mask bit-pack (36 bits) ----
    int pix0[4];
    uint64_t bits = 0;
    #pragma unroll
    for (int j = 0; j < 4; ++j) {
        const int ll = wn + j * 16 + lrow;           // block-local l 0..255
        pix0[j] = ((ll >> 6) + 1) * 66 + (ll & 63) + 1;
        const int lg = l0 + ll;
        #pragma unroll
        for (int k = 0; k < 9; ++k)
            if (mask[k * L_ + lg] != 0.0f) bits |= (1ull << (k * 4 + j));
    }

    floatx4 acc[4][4];
    #pragma unroll
    for (int i = 0; i < 4; ++i)
        #pragma unroll
        for (int j = 0; j < 4; ++j)
            acc[i][j] = (floatx4){0.f, 0.f, 0.f, 0.f};

    __syncthreads();   // drains window + A(0) staging

    // ---- main loop: 18 half-steps (tap = g>>1, c-half = g&1) ----
    for (int g = 0; g < 18; ++g) {
        const int k = g >> 1;

        // stage A(g+1) into the other buffer (its readers finished at the
        // barrier ending step g-1; the barrier ending THIS step drains it,
        // ~1300 cy after issue -> L2 latency covered)
        if (g < 17) {
            const int gn   = g + 1;
            const int koff = (gn >> 1) * 32768 + (gn & 1) * 128;
            char* dstb = A_c + (gn & 1) * 16384;
            async_copy16(wb2_c + koff + aoff0,         dstb + wv * 1024);
            async_copy16(wb2_c + koff + aoff0 + 16384, dstb + wv * 1024 + 8192);
        }

        const int sh = (k / 3 - 1) * 66 + (k % 3) - 1;   // window pixel shift
        uint32_t kp[4];
        #pragma unroll
        for (int j = 0; j < 4; ++j)
            kp[j] = 0u - (uint32_t)((bits >> (k * 4 + j)) & 1ull);

        const u16* Ac = (const u16*)(A_c + (g & 1) * 16384);

        #pragma unroll
        for (int ksl = 0; ksl < 2; ++ksl) {              // 32-c slices within half
            const int ksg = (g & 1) * 2 + ksl;           // global c-chunk quad 0..3
            bf16x8 af[4], bf[4];
            #pragma unroll
            for (int i = 0; i < 4; ++i) {
                const int orow = wm + i * 16 + lrow;
                const int slot = (ksl * 4 + quad) ^ (orow & 7);
                af[i] = *reinterpret_cast<const bf16x8*>(&Ac[orow * 64 + slot * 8]);
            }
            #pragma unroll
            for (int j = 0; j < 4; ++j) {
                const int pix  = pix0[j] + sh;
                const int slot = (ksg * 4 + quad) ^ (pix & 7);
                bf16x8 v = *reinterpret_cast<const bf16x8*>(&W_lds[pix * 128 + slot * 8]);
                u32x4 t = __builtin_bit_cast(u32x4, v);
                t &= kp[j];
                bf[j] = __builtin_bit_cast(bf16x8, t);
            }
            #pragma unroll
            for (int i = 0; i < 4; ++i)
                #pragma unroll
                for (int j = 0; j < 4; ++j)
                    acc[i][j] = __builtin_amdgcn_mfma_f32_16x16x32_bf16(
                        af[i], bf[j], acc[i][j], 0, 0, 0);
        }
        __syncthreads();   // readers done + next-A staging drained
    }

    // ---- epilogue: C/D layout col = lane&15 (l), row = quad*4 + r (o) ----
    #pragma unroll
    for (int i = 0; i < 4; ++i) {
        #pragma unroll
        for (int j = 0; j < 4; ++j) {
            const int l = l0 + wn + j * 16 + lrow;
            #pragma unroll
            for (int r = 0; r < 4; ++r) {
                const int o = wm + i * 16 + quad * 4 + r;
                out[((size_t)b * COUT_ + o) * L_ + l] = acc[i][j][r] + mb[o * L_ + l];
            }
        }
    }
}

// ---------------------------------------------------------------------------
extern "C" void kernel_launch(void* const* d_in, const int* in_sizes, int n_in,
                              void* d_out, int out_size, void* d_ws, size_t ws_size,
                              hipStream_t stream) {
    const float* x      = (const float*)d_in[0];
    const float* mask   = (const float*)d_in[1];
    const float* weight = (const float*)d_in[2];
    const float* mw     = (const float*)d_in[3];
    const float* bias   = (const float*)d_in[4];
    float* out = (float*)d_out;

    char* ws = (char*)d_ws;
    u16*   xTp = (u16*)ws;                                  // 16*4356*128*2 = 17,842,176 B
    u16*   wb2 = (u16*)(ws + 17842176);                     // 294,912 B  [9][128][128] bf16
    float* mb  = (float*)(ws + 17842176 + 294912);          // 2,097,152 B [128][4096] f32

    lmc_prep_kernel<<<1216, 256, 0, stream>>>(x, mask, mw, bias, weight, xTp, mb, wb2);
    lmc_gemm_kernel<<<256, 512, 0, stream>>>(xTp, wb2, mask, mb, out);
}